// Round 4
// baseline (407.921 us; speedup 1.0000x reference)
//
#include <hip/hip_runtime.h>
#include <hip/hip_cooperative_groups.h>
#include <math.h>

// MaskedBalancedBCELoss — hard-negative mining via count-histogram select.
//
// R14: fuse memset+k1+k5 into ONE cooperative kernel. Evidence: k1 is pinned
// at ~75us across three radically different load structures (R11 direct
// unrolled VGPR52; R12 high-occupancy; R13 3-deep global_load_lds pipeline,
// counted vmcnt) AND is invariant to data residency (L3-resident replays
// with 0.86MB HBM traffic run the same 75us as 80MB ones) -> the streaming
// rate (~2.1 TB/s) is not movable by load restructuring. Meanwhile total is
// 190us: ~115us is pipeline overhead (memset node + 2 kernel nodes + gaps).
// Fuse: phase0 zero ws -> grid.sync -> phase1 = R11 hot loop VERBATIM ->
// threadfence + grid.sync -> phase2 = block0 select (agent-scope atomic
// loads to dodge stale L1 from phase0's zero stores).
// Fallback to the proven 3-node path if cooperative launch fails.

#define NBINS1 4096
#define K1_BLOCKS 1024

struct Ctrl {
  unsigned long long pos_cnt;
  unsigned long long neg_cnt;
  unsigned long long k;
  double pos_sum;
  unsigned B;
  unsigned k_rem;
};

#define LN2F 0.69314718055994530942f

__device__ __forceinline__ double bin_mid(unsigned b) {
  return (double)__uint_as_float((b << 19) | 0x40000u);
}

// Per-element processing. Loss value bit-identical to R10..R13 (same
// expression tree) -> same bins -> midpoint model unchanged.
__device__ __forceinline__ void proc1(float p, float g, float m,
                                      unsigned& pc, unsigned& nc,
                                      double& psum, unsigned* __restrict__ hc) {
  bool gpos = (g != 0.0f);
  bool valid = (m != 0.0f);
  bool ispos = valid && gpos;
  bool isneg = valid && !gpos;
  float x = gpos ? p : 1.0f - p;
  float loss = -fmaxf(__log2f(x) * LN2F, -100.0f);
  pc += ispos ? 1u : 0u;
  nc += isneg ? 1u : 0u;
  psum += ispos ? (double)loss : 0.0;
  if (isneg) atomicAdd(&hc[__float_as_uint(loss) >> 19], 1u);
}

// ------------------------- fused cooperative kernel ------------------------
extern "C" __global__ void __launch_bounds__(256, 4)
mega(const float* __restrict__ pred, const float* __restrict__ gt,
     const float* __restrict__ mask, unsigned* __restrict__ hist1,
     Ctrl* __restrict__ ctrl, float* __restrict__ out, int n4, int n) {
  cooperative_groups::grid_group gg = cooperative_groups::this_grid();

  int gtid = blockIdx.x * blockDim.x + threadIdx.x;
  int S = gridDim.x * blockDim.x;

  // ---- phase 0: zero workspace (replaces hipMemsetAsync) ----
  for (int i = gtid; i < NBINS1; i += S) hist1[i] = 0u;
  if (gtid == 0) {
    ctrl->pos_cnt = 0ull; ctrl->neg_cnt = 0ull; ctrl->k = 0ull;
    ctrl->pos_sum = 0.0; ctrl->B = 0u; ctrl->k_rem = 0u;
  }

  // LDS hist zero can overlap phase 0 (block-local)
  __shared__ unsigned h[NBINS1];
  for (int i = threadIdx.x; i < NBINS1; i += blockDim.x) h[i] = 0u;

  gg.sync();

  // ---- phase 1: R11 hot loop, verbatim ----
  int wv = threadIdx.x >> 6, ln = threadIdx.x & 63;

  unsigned pc = 0, nc = 0;
  double psum = 0.0;
  const float4* p4 = (const float4*)pred;
  const float4* g4 = (const float4*)gt;
  const float4* m4 = (const float4*)mask;

  int i = gtid;
  for (; i + 3 * S < n4; i += 4 * S) {
    float4 pv0 = p4[i];
    float4 pv1 = p4[i + S];
    float4 pv2 = p4[i + 2 * S];
    float4 pv3 = p4[i + 3 * S];
    float4 gv0 = g4[i];
    float4 gv1 = g4[i + S];
    float4 gv2 = g4[i + 2 * S];
    float4 gv3 = g4[i + 3 * S];
    float4 mv0 = m4[i];
    float4 mv1 = m4[i + S];
    float4 mv2 = m4[i + 2 * S];
    float4 mv3 = m4[i + 3 * S];

    proc1(pv0.x, gv0.x, mv0.x, pc, nc, psum, h);
    proc1(pv0.y, gv0.y, mv0.y, pc, nc, psum, h);
    proc1(pv0.z, gv0.z, mv0.z, pc, nc, psum, h);
    proc1(pv0.w, gv0.w, mv0.w, pc, nc, psum, h);
    proc1(pv1.x, gv1.x, mv1.x, pc, nc, psum, h);
    proc1(pv1.y, gv1.y, mv1.y, pc, nc, psum, h);
    proc1(pv1.z, gv1.z, mv1.z, pc, nc, psum, h);
    proc1(pv1.w, gv1.w, mv1.w, pc, nc, psum, h);
    proc1(pv2.x, gv2.x, mv2.x, pc, nc, psum, h);
    proc1(pv2.y, gv2.y, mv2.y, pc, nc, psum, h);
    proc1(pv2.z, gv2.z, mv2.z, pc, nc, psum, h);
    proc1(pv2.w, gv2.w, mv2.w, pc, nc, psum, h);
    proc1(pv3.x, gv3.x, mv3.x, pc, nc, psum, h);
    proc1(pv3.y, gv3.y, mv3.y, pc, nc, psum, h);
    proc1(pv3.z, gv3.z, mv3.z, pc, nc, psum, h);
    proc1(pv3.w, gv3.w, mv3.w, pc, nc, psum, h);
  }
  for (; i < n4; i += S) {
    float4 pv = p4[i], gv = g4[i], mv = m4[i];
    proc1(pv.x, gv.x, mv.x, pc, nc, psum, h);
    proc1(pv.y, gv.y, mv.y, pc, nc, psum, h);
    proc1(pv.z, gv.z, mv.z, pc, nc, psum, h);
    proc1(pv.w, gv.w, mv.w, pc, nc, psum, h);
  }
  for (int t = n4 * 4 + gtid; t < n; t += S) {
    proc1(pred[t], gt[t], mask[t], pc, nc, psum, h);
  }

  // block reduce pc/nc/psum
  unsigned long long pcl = pc, ncl = nc;
  for (int off = 32; off > 0; off >>= 1) {
    pcl += __shfl_down(pcl, off);
    ncl += __shfl_down(ncl, off);
    psum += __shfl_down(psum, off);
  }
  __shared__ unsigned long long spc[4], snc[4];
  __shared__ double sps[4];
  if (ln == 0) { spc[wv] = pcl; snc[wv] = ncl; sps[wv] = psum; }
  __syncthreads();   // also ensures all LDS histogram atomics are complete
  if (threadIdx.x == 0) {
    unsigned long long tp = 0, tn = 0; double ts = 0.0;
    for (int w = 0; w < 4; w++) { tp += spc[w]; tn += snc[w]; ts += sps[w]; }
    atomicAdd(&ctrl->pos_cnt, tp);
    atomicAdd(&ctrl->neg_cnt, tn);
    unsafeAtomicAdd(&ctrl->pos_sum, ts);
  }
  // flush LDS histogram to global (skip empty bins)
  for (int b = threadIdx.x; b < NBINS1; b += blockDim.x) {
    unsigned c = h[b];
    if (c) atomicAdd(&hist1[b], c);
  }

  __threadfence();
  gg.sync();

  // ---- phase 2: select + midpoint neg_sum + output (block 0 only) ----
  if (blockIdx.x != 0) return;
  {
    const int T = 256, CH = NBINS1 / T;  // 16 bins per thread
    __shared__ unsigned long long sarr[T];
    __shared__ unsigned long long sk;
    __shared__ unsigned sB, skrem;
    __shared__ double sred[4];
    int t = threadIdx.x;

    unsigned cnt[CH];
    unsigned long long tot = 0;
    for (int j = 0; j < CH; j++) {
      cnt[j] = __hip_atomic_load(&hist1[t * CH + j], __ATOMIC_RELAXED,
                                 __HIP_MEMORY_SCOPE_AGENT);
      tot += cnt[j];
    }
    sarr[t] = tot;
    if (t == 0) {
      sB = 0xFFFFFFFFu; skrem = 0u;
      unsigned long long pos = __hip_atomic_load(&ctrl->pos_cnt, __ATOMIC_RELAXED,
                                                 __HIP_MEMORY_SCOPE_AGENT);
      unsigned long long negtot = __hip_atomic_load(&ctrl->neg_cnt, __ATOMIC_RELAXED,
                                                    __HIP_MEMORY_SCOPE_AGENT);
      unsigned long long k = 0;
      if (pos > 0) {               // FALLBACK_NEG=0 when pos==0
        k = pos * 3ull;            // floor(pos*3.0), exact in integer
        if (k > negtot) k = negtot;
      }
      ctrl->k = k;
      sk = k;
    }
    __syncthreads();
    // inclusive suffix scan: sarr[t] = sum over threads >= t
    for (int off = 1; off < T; off <<= 1) {
      unsigned long long v = (t + off < T) ? sarr[t + off] : 0ull;
      __syncthreads();
      sarr[t] += v;
      __syncthreads();
    }
    unsigned long long k = sk;
    if (k > 0) {
      unsigned long long above = sarr[t] - tot;
      if (above < k && sarr[t] >= k) {
        unsigned long long cum = above;
        for (int j = CH - 1; j >= 0; j--) {
          if (cum + (unsigned long long)cnt[j] >= k) {
            sB = (unsigned)(t * CH + j);
            skrem = (unsigned)(k - cum);
            break;
          }
          cum += cnt[j];
        }
      }
    }
    __syncthreads();
    unsigned B = sB;

    double s = 0.0;
    if (B != 0xFFFFFFFFu) {
      for (int j = 0; j < CH; j++) {
        unsigned bi = (unsigned)(t * CH + j);
        if (bi > B && cnt[j]) s += (double)cnt[j] * bin_mid(bi);
      }
    }
    for (int off = 32; off > 0; off >>= 1) s += __shfl_down(s, off);
    if (ln == 0) sred[wv] = s;
    __syncthreads();
    if (t == 0) {
      double neg_sum = sred[0] + sred[1] + sred[2] + sred[3];
      if (skrem > 0 && B != 0xFFFFFFFFu)
        neg_sum += (double)skrem * bin_mid(B);
      double pos_sum = __hip_atomic_load(&ctrl->pos_sum, __ATOMIC_RELAXED,
                                         __HIP_MEMORY_SCOPE_AGENT);
      double posd = (double)__hip_atomic_load(&ctrl->pos_cnt, __ATOMIC_RELAXED,
                                              __HIP_MEMORY_SCOPE_AGENT);
      double denom = posd + (double)k + 1e-6;
      out[0] = (float)((pos_sum + neg_sum) / denom);
    }
  }
}

// ------------- legacy 3-node fallback (R11 kernels, verbatim) --------------
extern "C" __global__ void __launch_bounds__(256, 4)
k1_hist(const float* __restrict__ pred, const float* __restrict__ gt,
        const float* __restrict__ mask, unsigned* __restrict__ hist1,
        Ctrl* __restrict__ ctrl, int n4, int n) {
  __shared__ unsigned h[NBINS1];
  for (int i = threadIdx.x; i < NBINS1; i += blockDim.x) h[i] = 0u;
  __syncthreads();

  int wv = threadIdx.x >> 6, ln = threadIdx.x & 63;
  unsigned pc = 0, nc = 0;
  double psum = 0.0;
  const float4* p4 = (const float4*)pred;
  const float4* g4 = (const float4*)gt;
  const float4* m4 = (const float4*)mask;
  int gtid = blockIdx.x * blockDim.x + threadIdx.x;
  int S = gridDim.x * blockDim.x;

  int i = gtid;
  for (; i + 3 * S < n4; i += 4 * S) {
    float4 pv0 = p4[i];
    float4 pv1 = p4[i + S];
    float4 pv2 = p4[i + 2 * S];
    float4 pv3 = p4[i + 3 * S];
    float4 gv0 = g4[i];
    float4 gv1 = g4[i + S];
    float4 gv2 = g4[i + 2 * S];
    float4 gv3 = g4[i + 3 * S];
    float4 mv0 = m4[i];
    float4 mv1 = m4[i + S];
    float4 mv2 = m4[i + 2 * S];
    float4 mv3 = m4[i + 3 * S];
    proc1(pv0.x, gv0.x, mv0.x, pc, nc, psum, h);
    proc1(pv0.y, gv0.y, mv0.y, pc, nc, psum, h);
    proc1(pv0.z, gv0.z, mv0.z, pc, nc, psum, h);
    proc1(pv0.w, gv0.w, mv0.w, pc, nc, psum, h);
    proc1(pv1.x, gv1.x, mv1.x, pc, nc, psum, h);
    proc1(pv1.y, gv1.y, mv1.y, pc, nc, psum, h);
    proc1(pv1.z, gv1.z, mv1.z, pc, nc, psum, h);
    proc1(pv1.w, gv1.w, mv1.w, pc, nc, psum, h);
    proc1(pv2.x, gv2.x, mv2.x, pc, nc, psum, h);
    proc1(pv2.y, gv2.y, mv2.y, pc, nc, psum, h);
    proc1(pv2.z, gv2.z, mv2.z, pc, nc, psum, h);
    proc1(pv2.w, gv2.w, mv2.w, pc, nc, psum, h);
    proc1(pv3.x, gv3.x, mv3.x, pc, nc, psum, h);
    proc1(pv3.y, gv3.y, mv3.y, pc, nc, psum, h);
    proc1(pv3.z, gv3.z, mv3.z, pc, nc, psum, h);
    proc1(pv3.w, gv3.w, mv3.w, pc, nc, psum, h);
  }
  for (; i < n4; i += S) {
    float4 pv = p4[i], gv = g4[i], mv = m4[i];
    proc1(pv.x, gv.x, mv.x, pc, nc, psum, h);
    proc1(pv.y, gv.y, mv.y, pc, nc, psum, h);
    proc1(pv.z, gv.z, mv.z, pc, nc, psum, h);
    proc1(pv.w, gv.w, mv.w, pc, nc, psum, h);
  }
  for (int t = n4 * 4 + gtid; t < n; t += S) {
    proc1(pred[t], gt[t], mask[t], pc, nc, psum, h);
  }

  unsigned long long pcl = pc, ncl = nc;
  for (int off = 32; off > 0; off >>= 1) {
    pcl += __shfl_down(pcl, off);
    ncl += __shfl_down(ncl, off);
    psum += __shfl_down(psum, off);
  }
  __shared__ unsigned long long spc[4], snc[4];
  __shared__ double sps[4];
  if (ln == 0) { spc[wv] = pcl; snc[wv] = ncl; sps[wv] = psum; }
  __syncthreads();
  if (threadIdx.x == 0) {
    unsigned long long tp = 0, tn = 0; double ts = 0.0;
    for (int w = 0; w < 4; w++) { tp += spc[w]; tn += snc[w]; ts += sps[w]; }
    atomicAdd(&ctrl->pos_cnt, tp);
    atomicAdd(&ctrl->neg_cnt, tn);
    unsafeAtomicAdd(&ctrl->pos_sum, ts);
  }
  for (int b = threadIdx.x; b < NBINS1; b += blockDim.x) {
    unsigned c = h[b];
    if (c) atomicAdd(&hist1[b], c);
  }
}

extern "C" __global__ void __launch_bounds__(256)
k5_final(const unsigned* __restrict__ hist1, Ctrl* __restrict__ ctrl,
         float* __restrict__ out) {
  const int T = 256, CH = NBINS1 / T;
  __shared__ unsigned long long sarr[T];
  __shared__ unsigned long long sk;
  __shared__ unsigned sB, skrem;
  __shared__ double sred[4];
  int t = threadIdx.x;
  int wv = t >> 6, ln = t & 63;

  unsigned cnt[CH];
  unsigned long long tot = 0;
  for (int j = 0; j < CH; j++) { cnt[j] = hist1[t * CH + j]; tot += cnt[j]; }
  sarr[t] = tot;
  if (t == 0) {
    sB = 0xFFFFFFFFu; skrem = 0u;
    unsigned long long pos = ctrl->pos_cnt, negtot = ctrl->neg_cnt;
    unsigned long long k = 0;
    if (pos > 0) {
      k = pos * 3ull;
      if (k > negtot) k = negtot;
    }
    ctrl->k = k;
    sk = k;
  }
  __syncthreads();
  for (int off = 1; off < T; off <<= 1) {
    unsigned long long v = (t + off < T) ? sarr[t + off] : 0ull;
    __syncthreads();
    sarr[t] += v;
    __syncthreads();
  }
  unsigned long long k = sk;
  if (k > 0) {
    unsigned long long above = sarr[t] - tot;
    if (above < k && sarr[t] >= k) {
      unsigned long long cum = above;
      for (int j = CH - 1; j >= 0; j--) {
        if (cum + (unsigned long long)cnt[j] >= k) {
          sB = (unsigned)(t * CH + j);
          skrem = (unsigned)(k - cum);
          break;
        }
        cum += cnt[j];
      }
    }
  }
  __syncthreads();
  unsigned B = sB;

  double s = 0.0;
  if (B != 0xFFFFFFFFu) {
    for (int j = 0; j < CH; j++) {
      unsigned bi = (unsigned)(t * CH + j);
      if (bi > B && cnt[j]) s += (double)cnt[j] * bin_mid(bi);
    }
  }
  for (int off = 32; off > 0; off >>= 1) s += __shfl_down(s, off);
  if (ln == 0) sred[wv] = s;
  __syncthreads();
  if (t == 0) {
    double neg_sum = sred[0] + sred[1] + sred[2] + sred[3];
    if (skrem > 0 && B != 0xFFFFFFFFu)
      neg_sum += (double)skrem * bin_mid(B);
    double denom = (double)ctrl->pos_cnt + (double)k + 1e-6;
    out[0] = (float)((ctrl->pos_sum + neg_sum) / denom);
  }
}

// ---------------------------------------------------------------------------
extern "C" void kernel_launch(void* const* d_in, const int* in_sizes, int n_in,
                              void* d_out, int out_size, void* d_ws, size_t ws_size,
                              hipStream_t stream) {
  const float* pred = (const float*)d_in[0];
  const float* gt   = (const float*)d_in[1];
  const float* mask = (const float*)d_in[2];
  float* out = (float*)d_out;
  int n = in_sizes[0];
  int n4 = n / 4;
  char* ws = (char*)d_ws;

  const size_t HIST1_OFF = 256;
  Ctrl* ctrl = (Ctrl*)ws;
  unsigned* hist1 = (unsigned*)(ws + HIST1_OFF);

  // one-time co-residency check for the cooperative launch
  static int coop_blocks = -1;
  if (coop_blocks < 0) {
    int nb = 0;
    hipError_t oe = hipOccupancyMaxActiveBlocksPerMultiprocessor(
        &nb, (const void*)mega, 256, 0);
    if (oe == hipSuccess && nb >= 1) {
      int cap = nb * 256;                       // 256 CUs on MI355X
      coop_blocks = (cap < K1_BLOCKS) ? cap : K1_BLOCKS;
    } else {
      coop_blocks = 0;
    }
  }

  if (coop_blocks > 0) {
    void* args[] = {(void*)&pred, (void*)&gt, (void*)&mask, (void*)&hist1,
                    (void*)&ctrl, (void*)&out, (void*)&n4, (void*)&n};
    hipError_t e = hipLaunchCooperativeKernel(
        (const void*)mega, dim3(coop_blocks), dim3(256), args, 0, stream);
    if (e == hipSuccess) return;
    coop_blocks = 0;  // don't retry the cooperative path
  }

  // fallback: proven 3-node pipeline (R11)
  const size_t ZERO_BYTES = HIST1_OFF + NBINS1 * sizeof(unsigned);   // 16640
  hipMemsetAsync(d_ws, 0, ZERO_BYTES, stream);
  k1_hist<<<K1_BLOCKS, 256, 0, stream>>>(pred, gt, mask, hist1, ctrl, n4, n);
  k5_final<<<1, 256, 0, stream>>>(hist1, ctrl, out);
}

// Round 5
// 235.453 us; speedup vs baseline: 1.7325x; 1.7325x over previous
//
#include <hip/hip_runtime.h>
#include <math.h>

// MaskedBalancedBCELoss — hard-negative mining via count-histogram select.
//
// R15: ABLATION ROUND. R14 post-mortem: fusion again wrecked hot-loop codegen
// (VGPR 36, 322us) -> revert to R11 3-node pipeline (best: 189us, k1=74.9).
// k1 is pinned at ~75us (2.1 TB/s) across FOUR load structures and is
// invariant to L3 residency; VALU/DS/HBM all <15% busy. Two suspects remain,
// indistinguishable from existing counters:
//   (a) the 3-stream vector-load path itself
//   (b) the per-element scattered LDS atomic RMW (deterministic pattern ->
//       explains bit-identical 942663 conflict count in every round)
// So: run the REAL R11 pipeline unchanged (correctness + baseline), then two
// diagnostic kernels on scratch:
//   ab_loads: exact 12-load structure, sums consumed, NO atomics/histogram
//   ab_atom : pred-only load + full-rate bin+LDS-atomic
// Both keep 16KB LDS + launch_bounds(256,4) to match k1 occupancy.
// Decode: whichever ablation sits at ~75us in the counter table is the wall.
// Total dur will regress this round (~300us) — accepted, diagnostic.

#define NBINS1 4096
#define K1_BLOCKS 1024

struct Ctrl {
  unsigned long long pos_cnt;
  unsigned long long neg_cnt;
  unsigned long long k;
  double pos_sum;
  unsigned B;
  unsigned k_rem;
};

#define LN2F 0.69314718055994530942f

__device__ __forceinline__ double bin_mid(unsigned b) {
  return (double)__uint_as_float((b << 19) | 0x40000u);
}

// Per-element processing. Loss value bit-identical to R10..R14 (same
// expression tree) -> same bins -> midpoint model unchanged.
__device__ __forceinline__ void proc1(float p, float g, float m,
                                      unsigned& pc, unsigned& nc,
                                      double& psum, unsigned* __restrict__ hc) {
  bool gpos = (g != 0.0f);
  bool valid = (m != 0.0f);
  bool ispos = valid && gpos;
  bool isneg = valid && !gpos;
  float x = gpos ? p : 1.0f - p;
  float loss = -fmaxf(__log2f(x) * LN2F, -100.0f);
  pc += ispos ? 1u : 0u;
  nc += isneg ? 1u : 0u;
  psum += ispos ? (double)loss : 0.0;
  if (isneg) atomicAdd(&hc[__float_as_uint(loss) >> 19], 1u);
}

// ---------------- Kernel 1: reductions + level-1 histogram -----------------
// R11 verbatim (74.9us measured, VGPR 52).
extern "C" __global__ void __launch_bounds__(256, 4)
k1_hist(const float* __restrict__ pred, const float* __restrict__ gt,
        const float* __restrict__ mask, unsigned* __restrict__ hist1,
        Ctrl* __restrict__ ctrl, int n4, int n) {
  __shared__ unsigned h[NBINS1];
  for (int i = threadIdx.x; i < NBINS1; i += blockDim.x) h[i] = 0u;
  __syncthreads();

  int wv = threadIdx.x >> 6, ln = threadIdx.x & 63;
  unsigned pc = 0, nc = 0;
  double psum = 0.0;
  const float4* p4 = (const float4*)pred;
  const float4* g4 = (const float4*)gt;
  const float4* m4 = (const float4*)mask;
  int gtid = blockIdx.x * blockDim.x + threadIdx.x;
  int S = gridDim.x * blockDim.x;

  int i = gtid;
  for (; i + 3 * S < n4; i += 4 * S) {
    float4 pv0 = p4[i];
    float4 pv1 = p4[i + S];
    float4 pv2 = p4[i + 2 * S];
    float4 pv3 = p4[i + 3 * S];
    float4 gv0 = g4[i];
    float4 gv1 = g4[i + S];
    float4 gv2 = g4[i + 2 * S];
    float4 gv3 = g4[i + 3 * S];
    float4 mv0 = m4[i];
    float4 mv1 = m4[i + S];
    float4 mv2 = m4[i + 2 * S];
    float4 mv3 = m4[i + 3 * S];
    proc1(pv0.x, gv0.x, mv0.x, pc, nc, psum, h);
    proc1(pv0.y, gv0.y, mv0.y, pc, nc, psum, h);
    proc1(pv0.z, gv0.z, mv0.z, pc, nc, psum, h);
    proc1(pv0.w, gv0.w, mv0.w, pc, nc, psum, h);
    proc1(pv1.x, gv1.x, mv1.x, pc, nc, psum, h);
    proc1(pv1.y, gv1.y, mv1.y, pc, nc, psum, h);
    proc1(pv1.z, gv1.z, mv1.z, pc, nc, psum, h);
    proc1(pv1.w, gv1.w, mv1.w, pc, nc, psum, h);
    proc1(pv2.x, gv2.x, mv2.x, pc, nc, psum, h);
    proc1(pv2.y, gv2.y, mv2.y, pc, nc, psum, h);
    proc1(pv2.z, gv2.z, mv2.z, pc, nc, psum, h);
    proc1(pv2.w, gv2.w, mv2.w, pc, nc, psum, h);
    proc1(pv3.x, gv3.x, mv3.x, pc, nc, psum, h);
    proc1(pv3.y, gv3.y, mv3.y, pc, nc, psum, h);
    proc1(pv3.z, gv3.z, mv3.z, pc, nc, psum, h);
    proc1(pv3.w, gv3.w, mv3.w, pc, nc, psum, h);
  }
  for (; i < n4; i += S) {
    float4 pv = p4[i], gv = g4[i], mv = m4[i];
    proc1(pv.x, gv.x, mv.x, pc, nc, psum, h);
    proc1(pv.y, gv.y, mv.y, pc, nc, psum, h);
    proc1(pv.z, gv.z, mv.z, pc, nc, psum, h);
    proc1(pv.w, gv.w, mv.w, pc, nc, psum, h);
  }
  for (int t = n4 * 4 + gtid; t < n; t += S) {
    proc1(pred[t], gt[t], mask[t], pc, nc, psum, h);
  }

  unsigned long long pcl = pc, ncl = nc;
  for (int off = 32; off > 0; off >>= 1) {
    pcl += __shfl_down(pcl, off);
    ncl += __shfl_down(ncl, off);
    psum += __shfl_down(psum, off);
  }
  __shared__ unsigned long long spc[4], snc[4];
  __shared__ double sps[4];
  if (ln == 0) { spc[wv] = pcl; snc[wv] = ncl; sps[wv] = psum; }
  __syncthreads();   // also ensures all LDS histogram atomics are complete
  if (threadIdx.x == 0) {
    unsigned long long tp = 0, tn = 0; double ts = 0.0;
    for (int w = 0; w < 4; w++) { tp += spc[w]; tn += snc[w]; ts += sps[w]; }
    atomicAdd(&ctrl->pos_cnt, tp);
    atomicAdd(&ctrl->neg_cnt, tn);
    unsafeAtomicAdd(&ctrl->pos_sum, ts);
  }
  for (int b = threadIdx.x; b < NBINS1; b += blockDim.x) {
    unsigned c = h[b];
    if (c) atomicAdd(&hist1[b], c);
  }
}

// ---------- Kernel 5: select + midpoint neg_sum + output (1 block) ---------
extern "C" __global__ void __launch_bounds__(256)
k5_final(const unsigned* __restrict__ hist1, Ctrl* __restrict__ ctrl,
         float* __restrict__ out) {
  const int T = 256, CH = NBINS1 / T;  // 16 bins per thread
  __shared__ unsigned long long sarr[T];
  __shared__ unsigned long long sk;
  __shared__ unsigned sB, skrem;
  __shared__ double sred[4];
  int t = threadIdx.x;
  int wv = t >> 6, ln = t & 63;

  unsigned cnt[CH];
  unsigned long long tot = 0;
  for (int j = 0; j < CH; j++) { cnt[j] = hist1[t * CH + j]; tot += cnt[j]; }
  sarr[t] = tot;
  if (t == 0) {
    sB = 0xFFFFFFFFu; skrem = 0u;
    unsigned long long pos = ctrl->pos_cnt, negtot = ctrl->neg_cnt;
    unsigned long long k = 0;
    if (pos > 0) {               // FALLBACK_NEG=0 when pos==0
      k = pos * 3ull;            // floor(pos*3.0), exact in integer
      if (k > negtot) k = negtot;
    }
    ctrl->k = k;
    sk = k;
  }
  __syncthreads();
  for (int off = 1; off < T; off <<= 1) {
    unsigned long long v = (t + off < T) ? sarr[t + off] : 0ull;
    __syncthreads();
    sarr[t] += v;
    __syncthreads();
  }
  unsigned long long k = sk;
  if (k > 0) {
    unsigned long long above = sarr[t] - tot;
    if (above < k && sarr[t] >= k) {
      unsigned long long cum = above;
      for (int j = CH - 1; j >= 0; j--) {
        if (cum + (unsigned long long)cnt[j] >= k) {
          sB = (unsigned)(t * CH + j);
          skrem = (unsigned)(k - cum);
          break;
        }
        cum += cnt[j];
      }
    }
  }
  __syncthreads();
  unsigned B = sB;

  double s = 0.0;
  if (B != 0xFFFFFFFFu) {
    for (int j = 0; j < CH; j++) {
      unsigned bi = (unsigned)(t * CH + j);
      if (bi > B && cnt[j]) s += (double)cnt[j] * bin_mid(bi);
    }
  }
  for (int off = 32; off > 0; off >>= 1) s += __shfl_down(s, off);
  if (ln == 0) sred[wv] = s;
  __syncthreads();
  if (t == 0) {
    double neg_sum = sred[0] + sred[1] + sred[2] + sred[3];
    if (skrem > 0 && B != 0xFFFFFFFFu)
      neg_sum += (double)skrem * bin_mid(B);
    double denom = (double)ctrl->pos_cnt + (double)k + 1e-6;
    out[0] = (float)((ctrl->pos_sum + neg_sum) / denom);
  }
}

// ------------------- Ablation A: 3-stream loads only -----------------------
// Exact 12-load structure of k1, sums consumed, NO histogram/atomics.
extern "C" __global__ void __launch_bounds__(256, 4)
ab_loads(const float* __restrict__ pred, const float* __restrict__ gt,
         const float* __restrict__ mask, float* __restrict__ scratch, int n4) {
  __shared__ unsigned hdummy[NBINS1];   // match k1's LDS footprint
  for (int i = threadIdx.x; i < NBINS1; i += blockDim.x) hdummy[i] = 0u;
  __syncthreads();

  const float4* p4 = (const float4*)pred;
  const float4* g4 = (const float4*)gt;
  const float4* m4 = (const float4*)mask;
  int gtid = blockIdx.x * blockDim.x + threadIdx.x;
  int S = gridDim.x * blockDim.x;

  float ax = 0.f, ay = 0.f, az = 0.f, aw = 0.f;
  int i = gtid;
  for (; i + 3 * S < n4; i += 4 * S) {
    float4 a0 = p4[i], a1 = p4[i + S], a2 = p4[i + 2 * S], a3 = p4[i + 3 * S];
    float4 b0 = g4[i], b1 = g4[i + S], b2 = g4[i + 2 * S], b3 = g4[i + 3 * S];
    float4 c0 = m4[i], c1 = m4[i + S], c2 = m4[i + 2 * S], c3 = m4[i + 3 * S];
    ax += a0.x + b0.x + c0.x + a1.x + b1.x + c1.x + a2.x + b2.x + c2.x + a3.x + b3.x + c3.x;
    ay += a0.y + b0.y + c0.y + a1.y + b1.y + c1.y + a2.y + b2.y + c2.y + a3.y + b3.y + c3.y;
    az += a0.z + b0.z + c0.z + a1.z + b1.z + c1.z + a2.z + b2.z + c2.z + a3.z + b3.z + c3.z;
    aw += a0.w + b0.w + c0.w + a1.w + b1.w + c1.w + a2.w + b2.w + c2.w + a3.w + b3.w + c3.w;
  }
  for (; i < n4; i += S) {
    float4 a = p4[i], b = g4[i], c = m4[i];
    ax += a.x + b.x + c.x;
    ay += a.y + b.y + c.y;
    az += a.z + b.z + c.z;
    aw += a.w + b.w + c.w;
  }
  float s = ax + ay + az + aw;
  for (int off = 32; off > 0; off >>= 1) s += __shfl_down(s, off);
  s += (float)hdummy[threadIdx.x & (NBINS1 - 1)];   // keep LDS alive
  if ((threadIdx.x & 63) == 0)
    scratch[blockIdx.x * 4 + (threadIdx.x >> 6)] = s;
}

// -------------- Ablation B: pred load + full-rate LDS atomics --------------
// Pred-only stream; every element treated as negative (max atomic rate).
extern "C" __global__ void __launch_bounds__(256, 4)
ab_atom(const float* __restrict__ pred, unsigned* __restrict__ shist, int n4) {
  __shared__ unsigned h[NBINS1];
  for (int i = threadIdx.x; i < NBINS1; i += blockDim.x) h[i] = 0u;
  __syncthreads();

  const float4* p4 = (const float4*)pred;
  int gtid = blockIdx.x * blockDim.x + threadIdx.x;
  int S = gridDim.x * blockDim.x;

  int i = gtid;
  for (; i + 3 * S < n4; i += 4 * S) {
    float4 v0 = p4[i], v1 = p4[i + S], v2 = p4[i + 2 * S], v3 = p4[i + 3 * S];
    float a[16] = {v0.x, v0.y, v0.z, v0.w, v1.x, v1.y, v1.z, v1.w,
                   v2.x, v2.y, v2.z, v2.w, v3.x, v3.y, v3.z, v3.w};
#pragma unroll
    for (int j = 0; j < 16; j++) {
      float loss = -fmaxf(__log2f(1.0f - a[j]) * LN2F, -100.0f);
      atomicAdd(&h[__float_as_uint(loss) >> 19], 1u);
    }
  }
  for (; i < n4; i += S) {
    float4 v = p4[i];
    float a[4] = {v.x, v.y, v.z, v.w};
#pragma unroll
    for (int j = 0; j < 4; j++) {
      float loss = -fmaxf(__log2f(1.0f - a[j]) * LN2F, -100.0f);
      atomicAdd(&h[__float_as_uint(loss) >> 19], 1u);
    }
  }
  __syncthreads();
  for (int b = threadIdx.x; b < NBINS1; b += blockDim.x) {
    unsigned c = h[b];
    if (c) atomicAdd(&shist[b], c);
  }
}

// ---------------------------------------------------------------------------
extern "C" void kernel_launch(void* const* d_in, const int* in_sizes, int n_in,
                              void* d_out, int out_size, void* d_ws, size_t ws_size,
                              hipStream_t stream) {
  const float* pred = (const float*)d_in[0];
  const float* gt   = (const float*)d_in[1];
  const float* mask = (const float*)d_in[2];
  float* out = (float*)d_out;
  int n = in_sizes[0];
  int n4 = n / 4;
  char* ws = (char*)d_ws;

  // layout: ctrl@0 (64B), hist1@256 (16KB) -> zero first 16640 bytes.
  // diagnostics: ab_loads scratch @64KB (16KB), ab_atom shist @80KB (16KB).
  const size_t HIST1_OFF = 256;
  const size_t ZERO_BYTES = HIST1_OFF + NBINS1 * sizeof(unsigned);   // 16640
  const size_t AB_SCRATCH_OFF = 64 * 1024;
  const size_t AB_SHIST_OFF = 80 * 1024;
  const size_t AB_END = 96 * 1024;

  Ctrl* ctrl = (Ctrl*)ws;
  unsigned* hist1 = (unsigned*)(ws + HIST1_OFF);

  hipMemsetAsync(d_ws, 0, ZERO_BYTES, stream);
  k1_hist<<<K1_BLOCKS, 256, 0, stream>>>(pred, gt, mask, hist1, ctrl, n4, n);
  k5_final<<<1, 256, 0, stream>>>(hist1, ctrl, out);

  // diagnostic ablations (write only to scratch; output unaffected)
  if (ws_size >= AB_END) {
    float* ab_scratch = (float*)(ws + AB_SCRATCH_OFF);
    unsigned* ab_shist = (unsigned*)(ws + AB_SHIST_OFF);
    ab_loads<<<K1_BLOCKS, 256, 0, stream>>>(pred, gt, mask, ab_scratch, n4);
    ab_atom<<<K1_BLOCKS, 256, 0, stream>>>(pred, ab_shist, n4);
  }
}